// Round 8
// baseline (80.905 us; speedup 1.0000x reference)
//
#include <hip/hip_runtime.h>

#define B_TOT 2048
#define NHEAD 3

typedef __attribute__((ext_vector_type(8))) short short8v;
typedef __attribute__((ext_vector_type(4))) float f32x4;

#define LOG2E 1.4426950408889634f

static __device__ __forceinline__ unsigned short f2bf(float x) {
    unsigned u = __builtin_bit_cast(unsigned, x);
    u += 0x7FFFu + ((u >> 16) & 1u);
    return (unsigned short)(u >> 16);
}
static __device__ __forceinline__ float bf2f(unsigned short s) {
    unsigned u = ((unsigned)s) << 16;
    return __builtin_bit_cast(float, u);
}
static __device__ __forceinline__ float exp2_fast(float x) {
    float r; asm("v_exp_f32 %0, %1" : "=v"(r) : "v"(x)); return r;
}

// ---------------------------------------------------------------------------
// Bias MLP precompute, pre-scaled by log2(e), laid out for COALESCED
// per-tile C-init loads:
//   bias2[((h*16 + mt*4 + nt) * 64 + lane) * 4 + r]
//     = log2e * ( relu(rp(n,m) @ w1 + b1) @ w2 + b2 )[h]
//   with n = 16*mt + 4*(lane>>4) + r, m = 16*nt + (lane&15)  (MFMA C layout).
// ---------------------------------------------------------------------------
__global__ __launch_bounds__(256) void bias_kernel(const float* __restrict__ w1,
                                                   const float* __restrict__ b1,
                                                   const float* __restrict__ w2,
                                                   const float* __restrict__ b2,
                                                   float* __restrict__ bias2) {
    int t = blockIdx.x * 256 + threadIdx.x;   // 0..12287
    int h = t >> 12;
    int lane = (t >> 6) & 63;
    int pair = t & 63;
    int g = lane >> 4, c = lane & 15;
    int mt = pair >> 4, nt = (pair >> 2) & 3, r = pair & 3;
    int n = 16 * mt + 4 * g + r;
    int m = 16 * nt + c;

    float d0 = (float)((n >> 3) - (m >> 3));
    float d1 = (float)((n & 7) - (m & 7));
    float r0 = (d0 > 0.f ? 1.f : (d0 < 0.f ? -1.f : 0.f)) * log1pf(fabsf(d0));
    float r1 = (d1 > 0.f ? 1.f : (d1 < 0.f ? -1.f : 0.f)) * log1pf(fabsf(d1));
    float a = 0.f;
    for (int j = 0; j < 256; j++) {
        float hd = fmaf(r0, w1[j], fmaf(r1, w1[256 + j], b1[j]));
        hd = fmaxf(hd, 0.f);
        a = fmaf(hd, w2[j * 3 + h], a);
    }
    bias2[((h * 16 + mt * 4 + nt) * 64 + lane) * 4 + r] = (a + b2[h]) * LOG2E;
}

// ---------------------------------------------------------------------------
// Main kernel: 1 wave = 1 (b,h) unit; 4 waves/block; no __syncthreads.
// Identical to round-7 passing kernel except occupancy control:
// amdgpu_waves_per_eu(4,4) pins exactly 4 waves/EU (4 blocks/CU with the
// 36.9KB LDS), giving the allocator a hard 128-VGPR budget — avoids the
// round-6 failure where launch_bounds(256,4) (a MIN) over-squeezed to 64
// VGPR and spilled kreg[64] to scratch.
// ---------------------------------------------------------------------------
__global__ __launch_bounds__(256) __attribute__((amdgpu_waves_per_eu(4, 4)))
void attn_kernel(const float* __restrict__ qkv,
                 const float* __restrict__ bias2,
                 float* __restrict__ out) {
    // per-wave 9216B region: q [64][36] f32 -> O [64][36] f32 -> P [64][72] bf16
    __shared__ float smem[4][64 * 36];

    const int t = threadIdx.x;
    const int w = t >> 6;
    const int lane = t & 63;
    const int h = blockIdx.x % 3;
    const int b = (blockIdx.x / 3) * 4 + w;

    float* Qs = smem[w];
    const float* base = qkv + (size_t)b * (64 * 288) + h * 32;
    const float QS = 0.17677669529663687f * LOG2E;   // 32^-0.5 * log2e

    // ---- q -> LDS (scaled), coalesced float4 ----
    {
        const int nr = lane >> 3, d0 = (lane & 7) * 4;
        #pragma unroll
        for (int s = 0; s < 8; s++) {
            int n = 8 * s + nr;
            float4 q4 = *(const float4*)(base + n * 288 + d0);
            q4.x *= QS; q4.y *= QS; q4.z *= QS; q4.w *= QS;
            *(float4*)(Qs + n * 36 + d0) = q4;
        }
    }

    // ---- k column (channel dd) into 64 regs, rows rotated by 4*H2 ----
    const int dd = lane & 31, H2 = lane >> 5;
    float kreg[64];
    #pragma unroll
    for (int t8 = 0; t8 < 8; t8++) {
        const int rb = ((t8 + 4 * H2) & 7) * 8;
        #pragma unroll
        for (int tx = 0; tx < 8; tx++)
            kreg[t8 * 8 + tx] = base[(rb + tx) * 288 + 96 + dd];
    }

    asm volatile("s_waitcnt lgkmcnt(0)" ::: "memory");

    // ---- stage 1: 8x8 cyclic conv, lane owns channel dd, rows y=4*H2+yi ----
    float acc[4][8];
    #pragma unroll
    for (int yi = 0; yi < 4; yi++)
        #pragma unroll
        for (int x = 0; x < 8; x++) acc[yi][x] = 0.f;

    #pragma unroll
    for (int u = 0; u < 8; u++) {
        float q8[8];
        #pragma unroll
        for (int v = 0; v < 8; v++) q8[v] = Qs[(u * 8 + v) * 36 + dd];
        #pragma unroll
        for (int yi = 0; yi < 4; yi++) {
            const int s = (yi - u) & 7;
            #pragma unroll
            for (int v = 0; v < 8; v++) {
                #pragma unroll
                for (int x = 0; x < 8; x++)
                    acc[yi][x] = fmaf(q8[v], kreg[s * 8 + ((x - v) & 7)], acc[yi][x]);
            }
        }
    }

    // ---- O into same LDS region ----
    #pragma unroll
    for (int yi = 0; yi < 4; yi++) {
        const int n = (4 * H2 + yi) * 8;
        #pragma unroll
        for (int x = 0; x < 8; x++)
            Qs[(n + x) * 36 + dd] = acc[yi][x];
    }
    asm volatile("s_waitcnt lgkmcnt(0)" ::: "memory");

    const int g = lane >> 4, c = lane & 15;

    // ---- A-frags of O (hi/lo bf16): row = 16*mt + c, k-chunk = 8*g ----
    short8v Oh[4], Ol[4];
    #pragma unroll
    for (int mt = 0; mt < 4; mt++) {
        const float* rp = Qs + (16 * mt + c) * 36 + 8 * g;
        float4 x0 = *(const float4*)rp;
        float4 x1 = *(const float4*)(rp + 4);
        float xs[8] = {x0.x, x0.y, x0.z, x0.w, x1.x, x1.y, x1.z, x1.w};
        #pragma unroll
        for (int j = 0; j < 8; j++) {
            unsigned short hb = f2bf(xs[j]);
            Oh[mt][j] = (short)hb;
            Ol[mt][j] = (short)f2bf(xs[j] - bf2f(hb));
        }
    }

    // ---- B-frags of V^T (hi/lo): element V[16*nt + c][8*g + j], from global ----
    short8v Vh[4], Vl[4];
    #pragma unroll
    for (int nt = 0; nt < 4; nt++) {
        const float* vp = base + (16 * nt + c) * 288 + 192 + 8 * g;
        float4 x0 = *(const float4*)vp;
        float4 x1 = *(const float4*)(vp + 4);
        float xs[8] = {x0.x, x0.y, x0.z, x0.w, x1.x, x1.y, x1.z, x1.w};
        #pragma unroll
        for (int j = 0; j < 8; j++) {
            unsigned short hb = f2bf(xs[j]);
            Vh[nt][j] = (short)hb;
            Vl[nt][j] = (short)f2bf(xs[j] - bf2f(hb));
        }
    }

    // ---- S = O * V^T via MFMA (bias C-init; 3 products hh+hl+lh ~= fp32) ----
    const float* bb = bias2 + (size_t)h * 16 * 256 + lane * 4;
    f32x4 S[4][4];
    #pragma unroll
    for (int mt = 0; mt < 4; mt++)
        #pragma unroll
        for (int nt = 0; nt < 4; nt++) {
            f32x4 a = __builtin_bit_cast(f32x4, *(const float4*)(bb + (mt * 4 + nt) * 256));
            a = __builtin_amdgcn_mfma_f32_16x16x32_bf16(Oh[mt], Vh[nt], a, 0, 0, 0);
            a = __builtin_amdgcn_mfma_f32_16x16x32_bf16(Oh[mt], Vl[nt], a, 0, 0, 0);
            a = __builtin_amdgcn_mfma_f32_16x16x32_bf16(Ol[mt], Vh[nt], a, 0, 0, 0);
            S[mt][nt] = a;
        }

    // ---- prefetch V for PV stage (raw f32, packed later) ----
    float vb[2][2][8];   // [kt][dt][j] = V[32*kt + 8*g + j][16*dt + c]
    #pragma unroll
    for (int kt = 0; kt < 2; kt++)
        #pragma unroll
        for (int dt = 0; dt < 2; dt++)
            #pragma unroll
            for (int j = 0; j < 8; j++)
                vb[kt][dt][j] = base[(32 * kt + 8 * g + j) * 288 + 192 + 16 * dt + c];

    // ---- softmax (max-subtracted, exp2 domain) ----
    float inv[4][4];
    #pragma unroll
    for (int mt = 0; mt < 4; mt++) {
        #pragma unroll
        for (int r = 0; r < 4; r++) {
            float m0 = fmaxf(fmaxf(S[mt][0][r], S[mt][1][r]), fmaxf(S[mt][2][r], S[mt][3][r]));
            m0 = fmaxf(m0, __shfl_xor(m0, 1, 64));
            m0 = fmaxf(m0, __shfl_xor(m0, 2, 64));
            m0 = fmaxf(m0, __shfl_xor(m0, 4, 64));
            m0 = fmaxf(m0, __shfl_xor(m0, 8, 64));
            float s0 = 0.f;
            #pragma unroll
            for (int nt = 0; nt < 4; nt++) {
                float e = exp2_fast(S[mt][nt][r] - m0);
                S[mt][nt][r] = e;
                s0 += e;
            }
            s0 += __shfl_xor(s0, 1, 64);
            s0 += __shfl_xor(s0, 2, 64);
            s0 += __shfl_xor(s0, 4, 64);
            s0 += __shfl_xor(s0, 8, 64);
            inv[mt][r] = 1.f / s0;
        }
    }

    // ---- P (unnormalized) -> LDS bf16 [64][72] (aliases O region; O consumed) ----
    unsigned short* Ps = (unsigned short*)Qs;
    #pragma unroll
    for (int mt = 0; mt < 4; mt++)
        #pragma unroll
        for (int nt = 0; nt < 4; nt++)
            #pragma unroll
            for (int r = 0; r < 4; r++)
                Ps[(16 * mt + 4 * g + r) * 72 + 16 * nt + c] = f2bf(S[mt][nt][r]);
    asm volatile("s_waitcnt lgkmcnt(0)" ::: "memory");

    // ---- P A-frags: row = 16*mt + c, k-chunk = 32*kt + 8*g ----
    short8v Pf[4][2];
    #pragma unroll
    for (int mt = 0; mt < 4; mt++)
        #pragma unroll
        for (int kt = 0; kt < 2; kt++)
            Pf[mt][kt] = *(const short8v*)(Ps + (16 * mt + c) * 72 + 32 * kt + 8 * g);

    // ---- V B-frags for PV (single bf16) ----
    short8v Vp[2][2];
    #pragma unroll
    for (int kt = 0; kt < 2; kt++)
        #pragma unroll
        for (int dt = 0; dt < 2; dt++)
            #pragma unroll
            for (int j = 0; j < 8; j++)
                Vp[kt][dt][j] = (short)f2bf(vb[kt][dt][j]);

    // ---- X = P * V via MFMA ----
    f32x4 X[4][2];
    #pragma unroll
    for (int mt = 0; mt < 4; mt++)
        #pragma unroll
        for (int dt = 0; dt < 2; dt++) {
            f32x4 a = {0.f, 0.f, 0.f, 0.f};
            a = __builtin_amdgcn_mfma_f32_16x16x32_bf16(Pf[mt][0], Vp[0][dt], a, 0, 0, 0);
            a = __builtin_amdgcn_mfma_f32_16x16x32_bf16(Pf[mt][1], Vp[1][dt], a, 0, 0, 0);
            X[mt][dt] = a;
        }

    // ---- normalize + store: out[b][n][h*32 + d] ----
    float* op = out + (size_t)b * (64 * 96) + h * 32;
    #pragma unroll
    for (int mt = 0; mt < 4; mt++)
        #pragma unroll
        for (int dt = 0; dt < 2; dt++)
            #pragma unroll
            for (int r = 0; r < 4; r++)
                op[(16 * mt + 4 * g + r) * 96 + 16 * dt + c] = X[mt][dt][r] * inv[mt][r];
}

extern "C" void kernel_launch(void* const* d_in, const int* in_sizes, int n_in,
                              void* d_out, int out_size, void* d_ws, size_t ws_size,
                              hipStream_t stream) {
    const float* qkv = (const float*)d_in[0];
    const float* w1  = (const float*)d_in[1];
    const float* b1  = (const float*)d_in[2];
    const float* w2  = (const float*)d_in[3];
    const float* b2  = (const float*)d_in[4];
    float* out = (float*)d_out;
    float* bias2 = (float*)d_ws;   // 3*16*64*4 floats = 48 KB

    bias_kernel<<<48, 256, 0, stream>>>(w1, b1, w2, b2, bias2);
    attn_kernel<<<(B_TOT / 4) * NHEAD, 256, 0, stream>>>(qkv, bias2, out);
}

// Round 10
// 78.608 us; speedup vs baseline: 1.0292x; 1.0292x over previous
//
#include <hip/hip_runtime.h>

#define B_TOT 2048
#define NHEAD 3

typedef __attribute__((ext_vector_type(8))) short short8v;
typedef __attribute__((ext_vector_type(4))) float f32x4;
typedef __attribute__((ext_vector_type(2))) float f32x2;

#define LOG2E 1.4426950408889634f

static __device__ __forceinline__ unsigned short f2bf(float x) {
    unsigned u = __builtin_bit_cast(unsigned, x);
    u += 0x7FFFu + ((u >> 16) & 1u);
    return (unsigned short)(u >> 16);
}
static __device__ __forceinline__ float bf2f(unsigned short s) {
    unsigned u = ((unsigned)s) << 16;
    return __builtin_bit_cast(float, u);
}
static __device__ __forceinline__ float exp2_fast(float x) {
    float r; asm("v_exp_f32 %0, %1" : "=v"(r) : "v"(x)); return r;
}

// ---------------------------------------------------------------------------
// Bias MLP precompute, pre-scaled by log2(e), laid out for COALESCED
// per-tile C-init loads:
//   bias2[((h*16 + mt*4 + nt) * 64 + lane) * 4 + r]
//     = log2e * ( relu(rp(n,m) @ w1 + b1) @ w2 + b2 )[h]
//   with n = 16*mt + 4*(lane>>4) + r, m = 16*nt + (lane&15)  (MFMA C layout).
// ---------------------------------------------------------------------------
__global__ __launch_bounds__(256) void bias_kernel(const float* __restrict__ w1,
                                                   const float* __restrict__ b1,
                                                   const float* __restrict__ w2,
                                                   const float* __restrict__ b2,
                                                   float* __restrict__ bias2) {
    int t = blockIdx.x * 256 + threadIdx.x;   // 0..12287
    int h = t >> 12;
    int lane = (t >> 6) & 63;
    int pair = t & 63;
    int g = lane >> 4, c = lane & 15;
    int mt = pair >> 4, nt = (pair >> 2) & 3, r = pair & 3;
    int n = 16 * mt + 4 * g + r;
    int m = 16 * nt + c;

    float d0 = (float)((n >> 3) - (m >> 3));
    float d1 = (float)((n & 7) - (m & 7));
    float r0 = (d0 > 0.f ? 1.f : (d0 < 0.f ? -1.f : 0.f)) * log1pf(fabsf(d0));
    float r1 = (d1 > 0.f ? 1.f : (d1 < 0.f ? -1.f : 0.f)) * log1pf(fabsf(d1));
    float a = 0.f;
    for (int j = 0; j < 256; j++) {
        float hd = fmaf(r0, w1[j], fmaf(r1, w1[256 + j], b1[j]));
        hd = fmaxf(hd, 0.f);
        a = fmaf(hd, w2[j * 3 + h], a);
    }
    bias2[((h * 16 + mt * 4 + nt) * 64 + lane) * 4 + r] = (a + b2[h]) * LOG2E;
}

// ---------------------------------------------------------------------------
// Main kernel: identical to the round-7 passing kernel (68.2us) except the
// conv uses packed f32x2 FMA over output pairs (p, p+4) with a DUAL
// accumulator (no op_sel — round 9 showed op_sel半swap is unreliable):
//   normal terms ((p-v)&4 == 0): accN[p] += q2 * kp   (.x->out[p], .y->out[p+4])
//   swapped terms ((p-v)&4 != 0): accR[p] += q2 * kp  (.x->out[p+4], .y->out[p])
// final: out[p] = accN.x + accR.y ; out[p+4] = accN.y + accR.x.
// __builtin_elementwise_fma on f32x2 -> v_pk_fma_f32 (or 2x v_fma, still exact).
// ---------------------------------------------------------------------------
__global__ __launch_bounds__(256, 3) void attn_kernel(const float* __restrict__ qkv,
                                                      const float* __restrict__ bias2,
                                                      float* __restrict__ out) {
    // per-wave 9216B region: q [64][36] f32 -> O [64][36] f32 -> P [64][72] bf16
    __shared__ float smem[4][64 * 36];

    const int t = threadIdx.x;
    const int w = t >> 6;
    const int lane = t & 63;
    const int h = blockIdx.x % 3;
    const int b = (blockIdx.x / 3) * 4 + w;

    float* Qs = smem[w];
    const float* base = qkv + (size_t)b * (64 * 288) + h * 32;
    const float QS = 0.17677669529663687f * LOG2E;   // 32^-0.5 * log2e

    // ---- q -> LDS (scaled), coalesced float4 ----
    {
        const int nr = lane >> 3, d0 = (lane & 7) * 4;
        #pragma unroll
        for (int s = 0; s < 8; s++) {
            int n = 8 * s + nr;
            float4 q4 = *(const float4*)(base + n * 288 + d0);
            q4.x *= QS; q4.y *= QS; q4.z *= QS; q4.w *= QS;
            *(float4*)(Qs + n * 36 + d0) = q4;
        }
    }

    // ---- k pairs (channel dd): kp[s*4+p] = {k[row s][p], k[row s][p+4]},
    // rows rotated by 4*H2 so conv register indices are compile-time ----
    const int dd = lane & 31, H2 = lane >> 5;
    f32x2 kp[32];
    #pragma unroll
    for (int t8 = 0; t8 < 8; t8++) {
        const int rb = ((t8 + 4 * H2) & 7) * 8;
        #pragma unroll
        for (int p = 0; p < 4; p++) {
            kp[t8 * 4 + p].x = base[(rb + p) * 288 + 96 + dd];
            kp[t8 * 4 + p].y = base[(rb + p + 4) * 288 + 96 + dd];
        }
    }

    asm volatile("s_waitcnt lgkmcnt(0)" ::: "memory");

    // ---- stage 1: 8x8 cyclic conv via packed FMA, dual accumulators ----
    f32x2 accN[4][4], accR[4][4];
    #pragma unroll
    for (int yi = 0; yi < 4; yi++)
        #pragma unroll
        for (int p = 0; p < 4; p++) {
            accN[yi][p] = (f32x2){0.f, 0.f};
            accR[yi][p] = (f32x2){0.f, 0.f};
        }

    #pragma unroll
    for (int u = 0; u < 8; u++) {
        f32x2 q2[8];
        #pragma unroll
        for (int v = 0; v < 8; v++) {
            float qv = Qs[(u * 8 + v) * 36 + dd];
            q2[v].x = qv; q2[v].y = qv;
        }
        #pragma unroll
        for (int yi = 0; yi < 4; yi++) {
            const int s = (yi - u) & 7;
            #pragma unroll
            for (int v = 0; v < 8; v++) {
                #pragma unroll
                for (int p = 0; p < 4; p++) {
                    const f32x2 k2 = kp[s * 4 + ((p - v) & 3)];
                    if ((p - v) & 4)
                        accR[yi][p] = __builtin_elementwise_fma(q2[v], k2, accR[yi][p]);
                    else
                        accN[yi][p] = __builtin_elementwise_fma(q2[v], k2, accN[yi][p]);
                }
            }
        }
    }

    // ---- O into same LDS region (combine dual accumulators) ----
    #pragma unroll
    for (int yi = 0; yi < 4; yi++) {
        const int n = (4 * H2 + yi) * 8;
        #pragma unroll
        for (int p = 0; p < 4; p++) {
            Qs[(n + p) * 36 + dd] = accN[yi][p].x + accR[yi][p].y;
            Qs[(n + p + 4) * 36 + dd] = accN[yi][p].y + accR[yi][p].x;
        }
    }
    asm volatile("s_waitcnt lgkmcnt(0)" ::: "memory");

    const int g = lane >> 4, c = lane & 15;

    // ---- A-frags of O (hi/lo bf16): row = 16*mt + c, k-chunk = 8*g ----
    short8v Oh[4], Ol[4];
    #pragma unroll
    for (int mt = 0; mt < 4; mt++) {
        const float* rp = Qs + (16 * mt + c) * 36 + 8 * g;
        float4 x0 = *(const float4*)rp;
        float4 x1 = *(const float4*)(rp + 4);
        float xs[8] = {x0.x, x0.y, x0.z, x0.w, x1.x, x1.y, x1.z, x1.w};
        #pragma unroll
        for (int j = 0; j < 8; j++) {
            unsigned short hb = f2bf(xs[j]);
            Oh[mt][j] = (short)hb;
            Ol[mt][j] = (short)f2bf(xs[j] - bf2f(hb));
        }
    }

    // ---- B-frags of V^T (hi/lo): element V[16*nt + c][8*g + j], from global ----
    short8v Vh[4], Vl[4];
    #pragma unroll
    for (int nt = 0; nt < 4; nt++) {
        const float* vp = base + (16 * nt + c) * 288 + 192 + 8 * g;
        float4 x0 = *(const float4*)vp;
        float4 x1 = *(const float4*)(vp + 4);
        float xs[8] = {x0.x, x0.y, x0.z, x0.w, x1.x, x1.y, x1.z, x1.w};
        #pragma unroll
        for (int j = 0; j < 8; j++) {
            unsigned short hb = f2bf(xs[j]);
            Vh[nt][j] = (short)hb;
            Vl[nt][j] = (short)f2bf(xs[j] - bf2f(hb));
        }
    }

    // ---- S = O * V^T via MFMA (bias C-init; 3 products hh+hl+lh ~= fp32) ----
    const float* bb = bias2 + (size_t)h * 16 * 256 + lane * 4;
    f32x4 S[4][4];
    #pragma unroll
    for (int mt = 0; mt < 4; mt++)
        #pragma unroll
        for (int nt = 0; nt < 4; nt++) {
            f32x4 a = __builtin_bit_cast(f32x4, *(const float4*)(bb + (mt * 4 + nt) * 256));
            a = __builtin_amdgcn_mfma_f32_16x16x32_bf16(Oh[mt], Vh[nt], a, 0, 0, 0);
            a = __builtin_amdgcn_mfma_f32_16x16x32_bf16(Oh[mt], Vl[nt], a, 0, 0, 0);
            a = __builtin_amdgcn_mfma_f32_16x16x32_bf16(Ol[mt], Vh[nt], a, 0, 0, 0);
            S[mt][nt] = a;
        }

    // ---- prefetch V for PV stage (raw f32, packed later) ----
    float vb[2][2][8];   // [kt][dt][j] = V[32*kt + 8*g + j][16*dt + c]
    #pragma unroll
    for (int kt = 0; kt < 2; kt++)
        #pragma unroll
        for (int dt = 0; dt < 2; dt++)
            #pragma unroll
            for (int j = 0; j < 8; j++)
                vb[kt][dt][j] = base[(32 * kt + 8 * g + j) * 288 + 192 + 16 * dt + c];

    // ---- softmax (max-subtracted, exp2 domain) ----
    float inv[4][4];
    #pragma unroll
    for (int mt = 0; mt < 4; mt++) {
        #pragma unroll
        for (int r = 0; r < 4; r++) {
            float m0 = fmaxf(fmaxf(S[mt][0][r], S[mt][1][r]), fmaxf(S[mt][2][r], S[mt][3][r]));
            m0 = fmaxf(m0, __shfl_xor(m0, 1, 64));
            m0 = fmaxf(m0, __shfl_xor(m0, 2, 64));
            m0 = fmaxf(m0, __shfl_xor(m0, 4, 64));
            m0 = fmaxf(m0, __shfl_xor(m0, 8, 64));
            float s0 = 0.f;
            #pragma unroll
            for (int nt = 0; nt < 4; nt++) {
                float e = exp2_fast(S[mt][nt][r] - m0);
                S[mt][nt][r] = e;
                s0 += e;
            }
            s0 += __shfl_xor(s0, 1, 64);
            s0 += __shfl_xor(s0, 2, 64);
            s0 += __shfl_xor(s0, 4, 64);
            s0 += __shfl_xor(s0, 8, 64);
            inv[mt][r] = 1.f / s0;
        }
    }

    // ---- P (unnormalized) -> LDS bf16 [64][72] (aliases O region; O consumed) ----
    unsigned short* Ps = (unsigned short*)Qs;
    #pragma unroll
    for (int mt = 0; mt < 4; mt++)
        #pragma unroll
        for (int nt = 0; nt < 4; nt++)
            #pragma unroll
            for (int r = 0; r < 4; r++)
                Ps[(16 * mt + 4 * g + r) * 72 + 16 * nt + c] = f2bf(S[mt][nt][r]);
    asm volatile("s_waitcnt lgkmcnt(0)" ::: "memory");

    // ---- P A-frags: row = 16*mt + c, k-chunk = 32*kt + 8*g ----
    short8v Pf[4][2];
    #pragma unroll
    for (int mt = 0; mt < 4; mt++)
        #pragma unroll
        for (int kt = 0; kt < 2; kt++)
            Pf[mt][kt] = *(const short8v*)(Ps + (16 * mt + c) * 72 + 32 * kt + 8 * g);

    // ---- V B-frags for PV (single bf16) ----
    short8v Vp[2][2];
    #pragma unroll
    for (int kt = 0; kt < 2; kt++)
        #pragma unroll
        for (int dt = 0; dt < 2; dt++)
            #pragma unroll
            for (int j = 0; j < 8; j++)
                Vp[kt][dt][j] = (short)f2bf(vb[kt][dt][j]);

    // ---- X = P * V via MFMA ----
    f32x4 X[4][2];
    #pragma unroll
    for (int mt = 0; mt < 4; mt++)
        #pragma unroll
        for (int dt = 0; dt < 2; dt++) {
            f32x4 a = {0.f, 0.f, 0.f, 0.f};
            a = __builtin_amdgcn_mfma_f32_16x16x32_bf16(Pf[mt][0], Vp[0][dt], a, 0, 0, 0);
            a = __builtin_amdgcn_mfma_f32_16x16x32_bf16(Pf[mt][1], Vp[1][dt], a, 0, 0, 0);
            X[mt][dt] = a;
        }

    // ---- normalize + store: out[b][n][h*32 + d] ----
    float* op = out + (size_t)b * (64 * 96) + h * 32;
    #pragma unroll
    for (int mt = 0; mt < 4; mt++)
        #pragma unroll
        for (int dt = 0; dt < 2; dt++)
            #pragma unroll
            for (int r = 0; r < 4; r++)
                op[(16 * mt + 4 * g + r) * 96 + 16 * dt + c] = X[mt][dt][r] * inv[mt][r];
}

extern "C" void kernel_launch(void* const* d_in, const int* in_sizes, int n_in,
                              void* d_out, int out_size, void* d_ws, size_t ws_size,
                              hipStream_t stream) {
    const float* qkv = (const float*)d_in[0];
    const float* w1  = (const float*)d_in[1];
    const float* b1  = (const float*)d_in[2];
    const float* w2  = (const float*)d_in[3];
    const float* b2  = (const float*)d_in[4];
    float* out = (float*)d_out;
    float* bias2 = (float*)d_ws;   // 3*16*64*4 floats = 48 KB

    bias_kernel<<<48, 256, 0, stream>>>(w1, b1, w2, b2, bias2);
    attn_kernel<<<(B_TOT / 4) * NHEAD, 256, 0, stream>>>(qkv, bias2, out);
}

// Round 12
// 66.320 us; speedup vs baseline: 1.2199x; 1.1853x over previous
//
#include <hip/hip_runtime.h>

#define B_TOT 2048
#define NHEAD 3

typedef __attribute__((ext_vector_type(8))) short short8v;
typedef __attribute__((ext_vector_type(4))) float f32x4;
typedef __attribute__((ext_vector_type(2))) __fp16 f16x2;

#define LOG2E 1.4426950408889634f

static __device__ __forceinline__ unsigned short f2bf(float x) {
    unsigned u = __builtin_bit_cast(unsigned, x);
    u += 0x7FFFu + ((u >> 16) & 1u);
    return (unsigned short)(u >> 16);
}
static __device__ __forceinline__ float bf2f(unsigned short s) {
    unsigned u = ((unsigned)s) << 16;
    return __builtin_bit_cast(float, u);
}
static __device__ __forceinline__ float exp2_fast(float x) {
    float r; asm("v_exp_f32 %0, %1" : "=v"(r) : "v"(x)); return r;
}

// ---------------------------------------------------------------------------
// Bias MLP precompute, pre-scaled by log2(e), laid out for COALESCED
// per-tile C-init loads:
//   bias2[((h*16 + mt*4 + nt) * 64 + lane) * 4 + r]
//     = log2e * ( relu(rp(n,m) @ w1 + b1) @ w2 + b2 )[h]
//   with n = 16*mt + 4*(lane>>4) + r, m = 16*nt + (lane&15)  (MFMA C layout).
// ---------------------------------------------------------------------------
__global__ __launch_bounds__(256) void bias_kernel(const float* __restrict__ w1,
                                                   const float* __restrict__ b1,
                                                   const float* __restrict__ w2,
                                                   const float* __restrict__ b2,
                                                   float* __restrict__ bias2) {
    int t = blockIdx.x * 256 + threadIdx.x;   // 0..12287
    int h = t >> 12;
    int lane = (t >> 6) & 63;
    int pair = t & 63;
    int g = lane >> 4, c = lane & 15;
    int mt = pair >> 4, nt = (pair >> 2) & 3, r = pair & 3;
    int n = 16 * mt + 4 * g + r;
    int m = 16 * nt + c;

    float d0 = (float)((n >> 3) - (m >> 3));
    float d1 = (float)((n & 7) - (m & 7));
    float r0 = (d0 > 0.f ? 1.f : (d0 < 0.f ? -1.f : 0.f)) * log1pf(fabsf(d0));
    float r1 = (d1 > 0.f ? 1.f : (d1 < 0.f ? -1.f : 0.f)) * log1pf(fabsf(d1));
    float a = 0.f;
    for (int j = 0; j < 256; j++) {
        float hd = fmaf(r0, w1[j], fmaf(r1, w1[256 + j], b1[j]));
        hd = fmaxf(hd, 0.f);
        a = fmaf(hd, w2[j * 3 + h], a);
    }
    bias2[((h * 16 + mt * 4 + nt) * 64 + lane) * 4 + r] = (a + b2[h]) * LOG2E;
}

// ---------------------------------------------------------------------------
// Main kernel: identical to the round-7 passing kernel (68.2us) except the
// conv contracts v-pairs with v_dot2_f32_f16 (__builtin_amdgcn_fdot2):
//   out[x] += q[2j]*k[(x-2j)&7] + q[2j+1]*k[(x-2j-1)&7]
//           = dot2( {q[2j],q[2j+1]},  krp[(x-2j)&7] ),
//   krp[i] = {k[i], k[(i-1)&7]}  (reversed-adjacent pair, f16x2).
// Scalar f32 accumulators (no register-pair alignment pressure — the
// round-9/10 pk_fma failure mode). 1024 dot2 replaces 2048 scalar FMA.
// ---------------------------------------------------------------------------
__global__ __launch_bounds__(256, 3) void attn_kernel(const float* __restrict__ qkv,
                                                      const float* __restrict__ bias2,
                                                      float* __restrict__ out) {
    // per-wave 9216B region: q [64][36] f32 -> O [64][36] f32 -> P [64][72] bf16
    __shared__ float smem[4][64 * 36];

    const int t = threadIdx.x;
    const int w = t >> 6;
    const int lane = t & 63;
    const int h = blockIdx.x % 3;
    const int b = (blockIdx.x / 3) * 4 + w;

    float* Qs = smem[w];
    const float* base = qkv + (size_t)b * (64 * 288) + h * 32;
    const float QS = 0.17677669529663687f * LOG2E;   // 32^-0.5 * log2e

    // ---- q -> LDS (scaled), coalesced float4 ----
    {
        const int nr = lane >> 3, d0 = (lane & 7) * 4;
        #pragma unroll
        for (int s = 0; s < 8; s++) {
            int n = 8 * s + nr;
            float4 q4 = *(const float4*)(base + n * 288 + d0);
            q4.x *= QS; q4.y *= QS; q4.z *= QS; q4.w *= QS;
            *(float4*)(Qs + n * 36 + d0) = q4;
        }
    }

    // ---- k reversed-pairs (channel dd), rows rotated by 4*H2 so conv
    // register indices are compile-time: krp[t8][i] = {k[i], k[(i-1)&7]} ----
    const int dd = lane & 31, H2 = lane >> 5;
    f16x2 krp[64];
    #pragma unroll
    for (int t8 = 0; t8 < 8; t8++) {
        const int rb = ((t8 + 4 * H2) & 7) * 8;
        float k8[8];
        #pragma unroll
        for (int tx = 0; tx < 8; tx++)
            k8[tx] = base[(rb + tx) * 288 + 96 + dd];
        #pragma unroll
        for (int i = 0; i < 8; i++)
            krp[t8 * 8 + i] = __builtin_amdgcn_cvt_pkrtz(k8[i], k8[(i - 1) & 7]);
    }

    asm volatile("s_waitcnt lgkmcnt(0)" ::: "memory");

    // ---- stage 1: 8x8 cyclic conv via f16 dot2, f32 accumulate ----
    // lane owns channel dd, rows y = 4*H2 + yi
    float acc[4][8];
    #pragma unroll
    for (int yi = 0; yi < 4; yi++)
        #pragma unroll
        for (int x = 0; x < 8; x++) acc[yi][x] = 0.f;

    #pragma unroll
    for (int u = 0; u < 8; u++) {
        f16x2 q2[4];
        #pragma unroll
        for (int j = 0; j < 4; j++) {
            float qa = Qs[(u * 8 + 2 * j) * 36 + dd];
            float qb = Qs[(u * 8 + 2 * j + 1) * 36 + dd];
            q2[j] = __builtin_amdgcn_cvt_pkrtz(qa, qb);
        }
        #pragma unroll
        for (int yi = 0; yi < 4; yi++) {
            const int s = (yi - u) & 7;
            #pragma unroll
            for (int x = 0; x < 8; x++) {
                #pragma unroll
                for (int j = 0; j < 4; j++)
                    acc[yi][x] = __builtin_amdgcn_fdot2(
                        q2[j], krp[s * 8 + ((x - 2 * j) & 7)], acc[yi][x], false);
            }
        }
    }

    // ---- O into same LDS region ----
    #pragma unroll
    for (int yi = 0; yi < 4; yi++) {
        const int n = (4 * H2 + yi) * 8;
        #pragma unroll
        for (int x = 0; x < 8; x++)
            Qs[(n + x) * 36 + dd] = acc[yi][x];
    }
    asm volatile("s_waitcnt lgkmcnt(0)" ::: "memory");

    const int g = lane >> 4, c = lane & 15;

    // ---- A-frags of O (hi/lo bf16): row = 16*mt + c, k-chunk = 8*g ----
    short8v Oh[4], Ol[4];
    #pragma unroll
    for (int mt = 0; mt < 4; mt++) {
        const float* rp = Qs + (16 * mt + c) * 36 + 8 * g;
        float4 x0 = *(const float4*)rp;
        float4 x1 = *(const float4*)(rp + 4);
        float xs[8] = {x0.x, x0.y, x0.z, x0.w, x1.x, x1.y, x1.z, x1.w};
        #pragma unroll
        for (int j = 0; j < 8; j++) {
            unsigned short hb = f2bf(xs[j]);
            Oh[mt][j] = (short)hb;
            Ol[mt][j] = (short)f2bf(xs[j] - bf2f(hb));
        }
    }

    // ---- B-frags of V^T (hi/lo): element V[16*nt + c][8*g + j], from global ----
    short8v Vh[4], Vl[4];
    #pragma unroll
    for (int nt = 0; nt < 4; nt++) {
        const float* vp = base + (16 * nt + c) * 288 + 192 + 8 * g;
        float4 x0 = *(const float4*)vp;
        float4 x1 = *(const float4*)(vp + 4);
        float xs[8] = {x0.x, x0.y, x0.z, x0.w, x1.x, x1.y, x1.z, x1.w};
        #pragma unroll
        for (int j = 0; j < 8; j++) {
            unsigned short hb = f2bf(xs[j]);
            Vh[nt][j] = (short)hb;
            Vl[nt][j] = (short)f2bf(xs[j] - bf2f(hb));
        }
    }

    // ---- S = O * V^T via MFMA (bias C-init; 3 products hh+hl+lh ~= fp32) ----
    const float* bb = bias2 + (size_t)h * 16 * 256 + lane * 4;
    f32x4 S[4][4];
    #pragma unroll
    for (int mt = 0; mt < 4; mt++)
        #pragma unroll
        for (int nt = 0; nt < 4; nt++) {
            f32x4 a = __builtin_bit_cast(f32x4, *(const float4*)(bb + (mt * 4 + nt) * 256));
            a = __builtin_amdgcn_mfma_f32_16x16x32_bf16(Oh[mt], Vh[nt], a, 0, 0, 0);
            a = __builtin_amdgcn_mfma_f32_16x16x32_bf16(Oh[mt], Vl[nt], a, 0, 0, 0);
            a = __builtin_amdgcn_mfma_f32_16x16x32_bf16(Ol[mt], Vh[nt], a, 0, 0, 0);
            S[mt][nt] = a;
        }

    // ---- prefetch V for PV stage (raw f32, packed later) ----
    float vb[2][2][8];   // [kt][dt][j] = V[32*kt + 8*g + j][16*dt + c]
    #pragma unroll
    for (int kt = 0; kt < 2; kt++)
        #pragma unroll
        for (int dt = 0; dt < 2; dt++)
            #pragma unroll
            for (int j = 0; j < 8; j++)
                vb[kt][dt][j] = base[(32 * kt + 8 * g + j) * 288 + 192 + 16 * dt + c];

    // ---- softmax (max-subtracted, exp2 domain) ----
    float inv[4][4];
    #pragma unroll
    for (int mt = 0; mt < 4; mt++) {
        #pragma unroll
        for (int r = 0; r < 4; r++) {
            float m0 = fmaxf(fmaxf(S[mt][0][r], S[mt][1][r]), fmaxf(S[mt][2][r], S[mt][3][r]));
            m0 = fmaxf(m0, __shfl_xor(m0, 1, 64));
            m0 = fmaxf(m0, __shfl_xor(m0, 2, 64));
            m0 = fmaxf(m0, __shfl_xor(m0, 4, 64));
            m0 = fmaxf(m0, __shfl_xor(m0, 8, 64));
            float s0 = 0.f;
            #pragma unroll
            for (int nt = 0; nt < 4; nt++) {
                float e = exp2_fast(S[mt][nt][r] - m0);
                S[mt][nt][r] = e;
                s0 += e;
            }
            s0 += __shfl_xor(s0, 1, 64);
            s0 += __shfl_xor(s0, 2, 64);
            s0 += __shfl_xor(s0, 4, 64);
            s0 += __shfl_xor(s0, 8, 64);
            inv[mt][r] = 1.f / s0;
        }
    }

    // ---- P (unnormalized) -> LDS bf16 [64][72] (aliases O region; O consumed) ----
    unsigned short* Ps = (unsigned short*)Qs;
    #pragma unroll
    for (int mt = 0; mt < 4; mt++)
        #pragma unroll
        for (int nt = 0; nt < 4; nt++)
            #pragma unroll
            for (int r = 0; r < 4; r++)
                Ps[(16 * mt + 4 * g + r) * 72 + 16 * nt + c] = f2bf(S[mt][nt][r]);
    asm volatile("s_waitcnt lgkmcnt(0)" ::: "memory");

    // ---- P A-frags: row = 16*mt + c, k-chunk = 32*kt + 8*g ----
    short8v Pf[4][2];
    #pragma unroll
    for (int mt = 0; mt < 4; mt++)
        #pragma unroll
        for (int kt = 0; kt < 2; kt++)
            Pf[mt][kt] = *(const short8v*)(Ps + (16 * mt + c) * 72 + 32 * kt + 8 * g);

    // ---- V B-frags for PV (single bf16) ----
    short8v Vp[2][2];
    #pragma unroll
    for (int kt = 0; kt < 2; kt++)
        #pragma unroll
        for (int dt = 0; dt < 2; dt++)
            #pragma unroll
            for (int j = 0; j < 8; j++)
                Vp[kt][dt][j] = (short)f2bf(vb[kt][dt][j]);

    // ---- X = P * V via MFMA ----
    f32x4 X[4][2];
    #pragma unroll
    for (int mt = 0; mt < 4; mt++)
        #pragma unroll
        for (int dt = 0; dt < 2; dt++) {
            f32x4 a = {0.f, 0.f, 0.f, 0.f};
            a = __builtin_amdgcn_mfma_f32_16x16x32_bf16(Pf[mt][0], Vp[0][dt], a, 0, 0, 0);
            a = __builtin_amdgcn_mfma_f32_16x16x32_bf16(Pf[mt][1], Vp[1][dt], a, 0, 0, 0);
            X[mt][dt] = a;
        }

    // ---- normalize + store: out[b][n][h*32 + d] ----
    float* op = out + (size_t)b * (64 * 96) + h * 32;
    #pragma unroll
    for (int mt = 0; mt < 4; mt++)
        #pragma unroll
        for (int dt = 0; dt < 2; dt++)
            #pragma unroll
            for (int r = 0; r < 4; r++)
                op[(16 * mt + 4 * g + r) * 96 + 16 * dt + c] = X[mt][dt][r] * inv[mt][r];
}

extern "C" void kernel_launch(void* const* d_in, const int* in_sizes, int n_in,
                              void* d_out, int out_size, void* d_ws, size_t ws_size,
                              hipStream_t stream) {
    const float* qkv = (const float*)d_in[0];
    const float* w1  = (const float*)d_in[1];
    const float* b1  = (const float*)d_in[2];
    const float* w2  = (const float*)d_in[3];
    const float* b2  = (const float*)d_in[4];
    float* out = (float*)d_out;
    float* bias2 = (float*)d_ws;   // 3*16*64*4 floats = 48 KB

    bias_kernel<<<48, 256, 0, stream>>>(w1, b1, w2, b2, bias2);
    attn_kernel<<<(B_TOT / 4) * NHEAD, 256, 0, stream>>>(qkv, bias2, out);
}